// Round 11
// baseline (113.122 us; speedup 1.0000x reference)
//
#include <hip/hip_runtime.h>
#include <stdint.h>

#define BATCH 32
#define H 512
#define W 512
#define NACC 16
#define TH 32              // center rows per tile
#define HALO 9             // coverage steps a=1..9
#define RH (TH + 2*HALO)   // 50 rows incl. halo
#define NWORDS (RH*8)      // 400 mask words per tile
#define NT 512             // R11: half-size blocks, 2 independent/CU
#define NW 8               // waves per block
#define NTILE (H/TH)       // 16
#define NBLK (NTILE*BATCH) // 512 blocks

// part[fid*NACC + k] per-tile partials (layout unchanged R0-R10):
//  0: sum(p*g)  1: sum(p)  2: sum(g)
//  3: cnt_pe 4: cnt_pm 5: cnt_pj  6: cnt_ge 7: cnt_gm 8: cnt_gj
//  9: int_e 10: int_m 11: int_j
// 12: dsum_p2g 13: cnt_p2g 14: dsum_g2p 15: cnt_g2p
//
// Journal: R1 spill >64 VGPR. R2 ticket merge -10us. R3 traffic neutral.
// R4 occupancy 2x flat. R5 VALU -15% flat. R6 ILP flat. R7 CSA-in-wave
// worse. R8 de-fuse worse. R9 balance flat. R10 -18% work ~flat.
// Signature: VALUBusy~Occ~35%, issue 2.5x below wall -> all waves of the
// mega-block stall together at phase boundaries. R11: same 16 waves/CU but
// as TWO independent 512-thread blocks -> two barrier domains per CU;
// one block's drain overlaps the other's compute. Phase internals are the
// proven R0/R4/R5 bodies. Dice bitwise-stable via virtual-wave emulation:
// real wave w accumulates R9's virtual waves {w, w+8} in two named pairs
// (parity selector u&1 is compile-time); redf keeps 16 slots.

__global__ __launch_bounds__(NT, 4) void fused_kernel(
    const float* __restrict__ pred, const float* __restrict__ gt,
    float* __restrict__ part)
{
    __shared__ uint64_t MpS[NWORDS + 2];   // pad word each end
    __shared__ uint64_t MgS[NWORDS + 2];
    __shared__ uint64_t Ge[TH * 8];        // gt class masks, center rows
    __shared__ uint64_t Gm[TH * 8];
    __shared__ uint64_t Gj[TH * 8];
    __shared__ float    EC[2][TH];         // pred colsums at cols 255|256
    __shared__ float    redf[16][2];       // 16 VIRTUAL wave slots
    __shared__ unsigned redu[NW][6];

    uint64_t* Mp = MpS + 1;   // flat index o = row*8 + word
    uint64_t* Mg = MgS + 1;

    // fid = tile*32 + b: all tiles of one image share an XCD (mod-8).
    int fid  = blockIdx.x;
    int b    = fid & 31;
    int tile = fid >> 5;

    const float* pimg = pred + (size_t)b * H * W;
    const float* gimg = gt   + (size_t)b * H * W;
    int y0 = tile * TH;
    int tid = threadIdx.x, lane = tid & 63, wid = tid >> 6;

    // ---- Phase 1: ballot masks + dice sums, rows y0-9..y0+40.
    // R0 loop with NW=8; wave w's tasks s=w+8m. Virtual wave (R9, mod 16):
    // m even -> vw=w (pair A), m odd -> vw=w+8 (pair B); u&1 == m&1 is
    // compile-time in the unrolled group -> static accumulator selection.
    // Per-pair task order ascending == R9's order -> dice bitwise identical.
    float v0A = 0.f, v1A = 0.f, v0B = 0.f, v1B = 0.f;
    for (int s0 = wid; s0 < NWORDS; s0 += 4 * NW) {
        float vp[4], vg[4];
        #pragma unroll
        for (int u = 0; u < 4; ++u) {
            int s = s0 + u * NW;
            vp[u] = 0.f; vg[u] = 0.f;
            int ry = y0 - HALO + (s >> 3);
            if (s < NWORDS && (unsigned)ry < (unsigned)H) {
                int i0 = ry * W + (s & 7) * 64 + lane;
                vp[u] = pimg[i0]; vg[u] = gimg[i0];
            }
        }
        #pragma unroll
        for (int u = 0; u < 4; ++u) {
            int s = s0 + u * NW;
            if (s < NWORDS) {                 // wave-uniform
                unsigned long long mp = __ballot(vp[u] > 0.5f);
                unsigned long long mg = __ballot(vg[u] > 0.5f);
                if (lane == 0) { Mp[s] = mp; Mg[s] = mg; }
                int r = s >> 3;
                if (r >= HALO && r < HALO + TH) {
                    if ((u & 1) == 0) {       // virtual wave w
                        v1A += vp[u];
                        v0A += (vg[u] > 0.5f) ? vp[u] : 0.f;
                    } else {                  // virtual wave w+8
                        v1B += vp[u];
                        v0B += (vg[u] > 0.5f) ? vp[u] : 0.f;
                    }
                }
            }
        }
    }
    if (tid == 0) { MpS[0] = 0; MpS[NWORDS + 1] = 0; MgS[0] = 0; MgS[NWORDS + 1] = 0; }

    // Stencil geometry (R0): 512 threads, 4 bands x 8 rows; prefetch two
    // pred rows pre-barrier (hidden under the drain).
    int qi = tid & 127, h2 = tid >> 7;
    int x4 = qi * 4;
    int ys = y0 + h2 * 8;
    float4 pm4 = make_float4(0, 0, 0, 0), pc4;
    if (ys > 0) pm4 = *(const float4*)(pimg + (size_t)(ys - 1) * W + x4);
    pc4 = *(const float4*)(pimg + (size_t)ys * W + x4);

    // pred edge colsums (cols 255,256)
    if (tid < 2 * TH) {
        int c = tid >> 5, r = tid & (TH - 1);
        int y = y0 + r, col = 255 + c;
        float sum = (y > 0     ? pimg[(size_t)(y - 1) * W + col] : 0.f)
                  +              pimg[(size_t)y * W + col]
                  + (y < H - 1 ? pimg[(size_t)(y + 1) * W + col] : 0.f);
        EC[c][r] = sum;
    }
    __syncthreads();                      // barrier 1: masks ready

    // ---- Bit-sliced gt classification (R5 CSA), threads 0-255.
    unsigned cge = 0, cgm = 0, cgj = 0;
    if (tid < 256) {
        int rr = tid >> 3, w = tid & 7;
        int oM = (HALO + rr) * 8 + w;
        bool wl = (w > 0), wr = (w < 7);
        uint64_t A  = Mg[oM - 8], Bm = Mg[oM], Cm = Mg[oM + 8];
        uint64_t AL = wl ? Mg[oM - 9] : 0ULL, AR = wr ? Mg[oM - 7] : 0ULL;
        uint64_t BL = wl ? Mg[oM - 1] : 0ULL, BR = wr ? Mg[oM + 1] : 0ULL;
        uint64_t CL = wl ? Mg[oM + 7] : 0ULL, CR = wr ? Mg[oM + 9] : 0ULL;
        uint64_t Aw = (A  << 1) | (AL >> 63), Ae = (A  >> 1) | (AR << 63);
        uint64_t Bw = (Bm << 1) | (BL >> 63), Be = (Bm >> 1) | (BR << 63);
        uint64_t Cw = (Cm << 1) | (CL >> 63), Ce = (Cm >> 1) | (CR << 63);
        uint64_t c1, c2, c3, c5, t;
        t = Aw ^ A;  uint64_t s1 = t ^ Ae;  c1 = (Aw & A)  | (Ae & t);
        t = Bw ^ Be; uint64_t s2 = t ^ Cw;  c2 = (Bw & Be) | (Cw & t);
        t = Cm ^ Ce; uint64_t s3 = t ^ s1;  c3 = (Cm & Ce) | (s1 & t);
        uint64_t b0 = s2 ^ s3, c4 = s2 & s3;
        t = c1 ^ c2; uint64_t s5 = t ^ c3;  c5 = (c1 & c2) | (c3 & t);
        uint64_t b1 = s5 ^ c4, c6 = s5 & c4;
        uint64_t b2 = c5 ^ c6, b3 = c5 & c6;
        uint64_t nz23 = ~(b2 | b3);
        uint64_t ge = Bm & b0 & ~b1 & nz23;
        uint64_t gm = Bm & b1 & ~b0 & nz23;
        uint64_t gj = Bm & (b2 | b3 | (b1 & b0));
        Ge[tid] = ge; Gm[tid] = gm; Gj[tid] = gj;
        cge = (unsigned)__popcll(ge);
        cgm = (unsigned)__popcll(gm);
        cgj = (unsigned)__popcll(gj);
    }

    // ---- Distance (R4 u64 cascade + bit-exact early exit), 512 threads:
    // waves 0-3 p2g, waves 4-7 g2p, one u64 word each.
    int dsum = 0, dcnt = 0;
    {
        bool isP = tid < 256;
        int di = tid & 255;
        int o  = (HALO + (di >> 3)) * 8 + (di & 7);
        int w  = di & 7;
        bool wL = (w > 0), wR = (w < 7);
        const uint64_t* MT = isP ? Mp : Mg;
        const uint64_t* MV = isP ? Mg : Mp;

        uint64_t T = MT[o];
        dcnt = __popcll(T);
        dsum = dcnt;                           // a=0 baseline (dist >= 1)
        uint64_t VM = MV[o];
        uint64_t VL = wL ? MV[o - 1] : 0ULL;
        uint64_t VR = wR ? MV[o + 1] : 0ULL;
        uint64_t C = VM;

        #pragma unroll
        for (int a = 1; a <= 9; ++a) {
            int lo = o - 8 * a, hi = o + 8 * a;
            uint64_t NM = MV[lo] | MV[hi];
            uint64_t NL = wL ? (MV[lo - 1] | MV[hi - 1]) : 0ULL;
            uint64_t NR = wR ? (MV[lo + 1] | MV[hi + 1]) : 0ULL;
            uint64_t SL = NL, SM = NM, SR = NR;
            const int m = a - 1;
            if (m >= 1) {
                SM |= (SM << 1) | (SM >> 1) | (SL >> 63) | (SR << 63);
                SL |= SL << 1; SR |= SR >> 1;
            }
            if (m >= 2) {
                const int s = (m == 2) ? 1 : 2;
                SM |= (SM << s) | (SM >> s) | (SL >> (64 - s)) | (SR << (64 - s));
                SL |= SL << s; SR |= SR >> s;
            }
            if (m >= 4) {
                const int s = (m - 3 < 4) ? (m - 3) : 4;
                SM |= (SM << s) | (SM >> s) | (SL >> (64 - s)) | (SR << (64 - s));
                SL |= SL << s; SR |= SR >> s;
            }
            if (m >= 8) {
                const int s = m - 7;
                SM |= (SM << s) | (SM >> s) | (SL >> (64 - s)) | (SR << (64 - s));
                SL |= SL << s; SR |= SR >> s;
            }
            C |= SM;
            VL |= NL; VM |= NM; VR |= NR;
            C |= (VM << a) | (VM >> a) | (VL >> (64 - a)) | (VR << (64 - a));
            uint64_t rem = T & ~C;
            dsum += __popcll(rem);
            if (__all(rem == 0ULL)) break;     // bit-exact (C monotone)
        }
    }
    __syncthreads();                      // barrier 2: class masks ready

    // ---- Stencil (R5 body): 8 rows/thread, pred rolling global float4,
    // gt via class-mask bit tests.
    uint64_t cpack = 0ULL;                 // 6 fields, max 32 < 127
    {
        int wdx = qi >> 4;
        int ss = (qi & 15) * 4;
        for (int r = 0; r < 8; ++r) {
            int y = ys + r;
            float4 pp4 = (y < H - 1) ? *(const float4*)(pimg + (size_t)(y + 1) * W + x4)
                                     : make_float4(0, 0, 0, 0);
            int ry = h2 * 8 + r;
            uint64_t gew = Ge[ry * 8 + wdx];
            uint64_t gmw = Gm[ry * 8 + wdx];
            uint64_t gjw = Gj[ry * 8 + wdx];

            float ps[6];
            ps[1] = pm4.x + pc4.x + pp4.x; ps[2] = pm4.y + pc4.y + pp4.y;
            ps[3] = pm4.z + pc4.z + pp4.z; ps[4] = pm4.w + pc4.w + pp4.w;
            float psl = __shfl_up(ps[4], 1, 64);
            float psr = __shfl_down(ps[1], 1, 64);
            if (lane == 0)  psl = (qi == 0)   ? 0.f : EC[0][ry];
            if (lane == 63) psr = (qi == 127) ? 0.f : EC[1][ry];
            ps[0] = psl; ps[5] = psr;

            float pcv[4] = {pc4.x, pc4.y, pc4.z, pc4.w};
            #pragma unroll
            for (int j = 0; j < 4; ++j) {
                float np = ps[j] + ps[j + 1] + ps[j + 2] - pcv[j];
                bool pon = pcv[j] > 0.5f;
                bool pe  = pon && (np == 1.f);
                bool pmb = pon && (np == 2.f);
                bool pjb = pon && (np > 2.f);
                unsigned geb = (unsigned)(gew >> (ss + j)) & 1u;
                unsigned gmb = (unsigned)(gmw >> (ss + j)) & 1u;
                unsigned gjb = (unsigned)(gjw >> (ss + j)) & 1u;
                cpack += (uint64_t)pe
                       | ((uint64_t)pmb << 7)
                       | ((uint64_t)pjb << 14)
                       | ((uint64_t)(pe  && geb) << 21)
                       | ((uint64_t)(pmb && gmb) << 28)
                       | ((uint64_t)(pjb && gjb) << 35);
            }
            pm4 = pc4; pc4 = pp4;
        }
    }

    // ---- Packed reductions: 4 floats + 6 u32. Bounds: cpack fields
    // <=64*32=2048, class counts <=64*64=4096, dsum <=64*640=40960 < 2^16.
    unsigned c_pe = (unsigned)( cpack        & 0x7F);
    unsigned c_pm = (unsigned)((cpack >> 7 ) & 0x7F);
    unsigned c_pj = (unsigned)((cpack >> 14) & 0x7F);
    unsigned c_ie = (unsigned)((cpack >> 21) & 0x7F);
    unsigned c_im = (unsigned)((cpack >> 28) & 0x7F);
    unsigned c_ij = (unsigned)((cpack >> 35) & 0x7F);
    unsigned r0 = (unsigned)dsum | ((unsigned)dcnt << 16);
    unsigned r1 = c_pe | (c_pm << 16);
    unsigned r2 = c_pj | (c_ie << 16);
    unsigned r3 = c_im | (c_ij << 16);
    unsigned r4 = cge | (cgm << 16);
    unsigned r5 = cgj;
    #pragma unroll
    for (int off = 32; off; off >>= 1) {
        v0A += __shfl_down(v0A, off, 64);
        v1A += __shfl_down(v1A, off, 64);
        v0B += __shfl_down(v0B, off, 64);
        v1B += __shfl_down(v1B, off, 64);
        r0 += __shfl_down(r0, off, 64);
        r1 += __shfl_down(r1, off, 64);
        r2 += __shfl_down(r2, off, 64);
        r3 += __shfl_down(r3, off, 64);
        r4 += __shfl_down(r4, off, 64);
        r5 += __shfl_down(r5, off, 64);
    }
    if (lane == 0) {
        redf[wid][0] = v0A;     redf[wid][1] = v1A;       // virtual wave w
        redf[wid + 8][0] = v0B; redf[wid + 8][1] = v1B;   // virtual wave w+8
        redu[wid][0] = r0; redu[wid][1] = r1; redu[wid][2] = r2;
        redu[wid][3] = r3; redu[wid][4] = r4; redu[wid][5] = r5;
    }
    __syncthreads();
    if (tid < 16) {
        int k = tid;
        float s = 0.f;
        if (k < 2) {
            #pragma unroll
            for (int wv = 0; wv < 16; ++wv) s += redf[wv][k];  // R9 order
        } else {
            // k: 2..15 -> (waveBase, waveCnt, reg, hi16)
            static const uint8_t WB[16] = {0,0, 4, 0,0,0, 0,0,0, 0,0,0, 0,0,4,4};
            static const uint8_t WC[16] = {0,0, 4, 8,8,8, 4,4,4, 8,8,8, 4,4,4,4};
            static const uint8_t RG[16] = {0,0, 0, 1,1,2, 4,4,5, 2,3,3, 0,0,0,0};
            static const uint8_t HI[16] = {0,0, 1, 0,1,0, 0,1,0, 1,0,1, 0,1,0,1};
            unsigned u = 0;
            for (int wv = WB[k]; wv < WB[k] + WC[k]; ++wv)
                u += (redu[wv][RG[k]] >> (HI[k] * 16)) & 0xFFFFu;
            s = (float)u;
        }
        part[fid * NACC + k] = s;
    }
}

// ---------------------------------------------------------------------------
// Final: reduce 512x16 partials -> 32x16 -> scalar. Unchanged (bit-exact).
// ---------------------------------------------------------------------------
__global__ __launch_bounds__(512) void final_kernel(
    const float* __restrict__ part, float* __restrict__ out)
{
    __shared__ float sacc[BATCH][NACC];
    __shared__ float tri[BATCH][3];
    int t = threadIdx.x;
    {
        int b = t >> 4, k = t & 15;
        float s = 0.f;
        #pragma unroll 4
        for (int j = 0; j < NTILE; ++j)            // fid = j*32 + b
            s += part[((j << 5) + b) * NACC + k];
        sacc[b][k] = s;
    }
    __syncthreads();
    if (t < BATCH) {
        const float* a = sacc[t];
        float inter = a[0], psum = a[1], gsum = a[2];
        float dice = (2.f * inter + 1.f) / (psum + gsum + 1.f);

        float pe = a[3], pm = a[4], pj = a[5];
        float ge = a[6], gm = a[7], gj = a[8];
        float ie = a[9], im = a[10], ij = a[11];
        float e_iou = (ie + 1.f) / (pe + ge - ie + 1.f);
        float m_iou = (im + 1.f) / (pm + gm - im + 1.f);
        float j_iou = (ij + 1.f) / (pj + gj - ij + 1.f);
        float total = ge + gj + gm + 1.f;
        float sloss = 1.f - ((ge / total) * e_iou + (gj / total) * j_iou + (gm / total) * m_iou);

        float p2g = a[12] / (a[13] + 1.f);
        float g2p = a[14] / (a[15] + 1.f);
        float med = ((p2g + g2p) * 0.5f) / 10.f;
        tri[t][0] = dice; tri[t][1] = sloss; tri[t][2] = med;
    }
    __syncthreads();
    if (t == 0) {
        float dice = 0.f, sloss = 0.f, med = 0.f;
        for (int b = 0; b < BATCH; ++b) {
            dice += tri[b][0]; sloss += tri[b][1]; med += tri[b][2];
        }
        float dice_loss  = 1.f - dice / (float)BATCH;
        float structural = sloss / (float)BATCH;
        float medial     = med / (float)BATCH;
        float avg = (dice_loss + structural + medial) / 3.f;
        float r = dice_loss  / (dice_loss  + 1.f) * avg
                + structural / (structural + 1.f) * avg
                + medial     / (medial     + 1.f) * avg;
        out[0] = r;
    }
}

extern "C" void kernel_launch(void* const* d_in, const int* in_sizes, int n_in,
                              void* d_out, int out_size, void* d_ws, size_t ws_size,
                              hipStream_t stream)
{
    const float* pred = (const float*)d_in[0];
    const float* gt   = (const float*)d_in[1];
    float* part = (float*)d_ws;
    float* out  = (float*)d_out;

    fused_kernel<<<dim3(NBLK), NT, 0, stream>>>(pred, gt, part);
    final_kernel<<<1, 512, 0, stream>>>(part, out);
}

// Round 13
// 110.383 us; speedup vs baseline: 1.0248x; 1.0248x over previous
//
#include <hip/hip_runtime.h>
#include <stdint.h>

#define BATCH 32
#define H 512
#define W 512
#define NACC 16
#define TH2 64             // rows per block (two 32-row part-tiles A,B)
#define HALO 9
#define RH2 (TH2 + 2*HALO) // 82 rows incl. halo
#define NW2 (RH2*8)        // 656 mask words per block
#define NT 1024
#define NW 16              // waves per block
#define NTILE 16           // 32-row part-tiles per image (unchanged layout)
#define NBLK2 (BATCH * (H/TH2))   // 256 blocks = 1/CU

// part[fid*NACC+k], fid = tile32*32 + b  (layout unchanged from R0-R9):
//  0: sum(p*g)  1: sum(p)  2: sum(g)
//  3: cnt_pe 4: cnt_pm 5: cnt_pj  6: cnt_ge 7: cnt_gm 8: cnt_gj
//  9: int_e 10: int_m 11: int_j
// 12: dsum_p2g 13: cnt_p2g 14: dsum_g2p 15: cnt_g2p
//
// Journal: R1 spill >64 VGPR. R2 ticket merge -10us. R3 traffic neutral.
// R4 occupancy 2x flat. R5 VALU -15% flat. R6 ILP flat. R7 CSA-in-wave
// worse. R8 de-fuse worse. R9 balance flat. R10 TH=64: BEST (110.67us,
// fused 41.3). R11 512-thread blocks: worse (halo refetch > decoupling).
// R12: infra failure (container), not kernel. R13: resubmit R10 verbatim.
// Ceiling: fused issue ~15us of 42us wall; remainder is distributed
// dependency stall across three latency-bound phases at 4 waves/SIMD;
// 9 orthogonal levers flat.

__global__ __launch_bounds__(NT, 4) void fused_kernel(
    const float* __restrict__ pred, const float* __restrict__ gt,
    float* __restrict__ part)
{
    __shared__ uint64_t MpS[NW2 + 2];      // pad word each end
    __shared__ uint64_t MgS[NW2 + 2];
    __shared__ uint64_t Ge[TH2 * 8];       // gt class masks, 64 center rows
    __shared__ uint64_t Gm[TH2 * 8];
    __shared__ uint64_t Gj[TH2 * 8];
    __shared__ float    EC[2][TH2];        // pred colsums at cols 255|256
    __shared__ float    redfA[NW][2], redfB[NW][2];
    __shared__ unsigned redu[NW][7];

    uint64_t* Mp = MpS + 1;   // flat index o = row*8 + word (row rel y0-9)
    uint64_t* Mg = MgS + 1;

    int fid  = blockIdx.x;
    int b    = fid & 31;      // image; fid%8 = b%8 -> image tiles share XCD
    int t64  = fid >> 5;      // 64-row tile index 0..7
    const float* pimg = pred + (size_t)b * H * W;
    const float* gimg = gt   + (size_t)b * H * W;
    int y0 = t64 * TH2;
    int tid = threadIdx.x, lane = tid & 63, wid = tid >> 6;

    // ---- Phase 1: ballot masks + dice sums, rows y0-9..y0+72 (each once).
    // A-center tasks t in [72,328), B-center in [328,584): per-wave ascending
    // stride-16 order == R9's per-subtile order -> dice bitwise identical.
    float v0A = 0.f, v1A = 0.f, v0B = 0.f, v1B = 0.f;
    for (int s0 = wid; s0 < NW2; s0 += 4 * NW) {
        float vp[4], vg[4];
        #pragma unroll
        for (int u = 0; u < 4; ++u) {
            int s = s0 + u * NW;
            vp[u] = 0.f; vg[u] = 0.f;
            int ry = y0 - HALO + (s >> 3);
            if (s < NW2 && (unsigned)ry < (unsigned)H) {
                int i0 = ry * W + (s & 7) * 64 + lane;
                vp[u] = pimg[i0]; vg[u] = gimg[i0];
            }
        }
        #pragma unroll
        for (int u = 0; u < 4; ++u) {
            int s = s0 + u * NW;
            if (s < NW2) {                    // wave-uniform
                unsigned long long mp = __ballot(vp[u] > 0.5f);
                unsigned long long mg = __ballot(vg[u] > 0.5f);
                if (lane == 0) { Mp[s] = mp; Mg[s] = mg; }
                if (s >= 72 && s < 328) {             // A center rows
                    v1A += vp[u];
                    v0A += (vg[u] > 0.5f) ? vp[u] : 0.f;
                } else if (s >= 328 && s < 584) {     // B center rows
                    v1B += vp[u];
                    v0B += (vg[u] > 0.5f) ? vp[u] : 0.f;
                }
            }
        }
    }
    if (tid == 0) { MpS[0] = 0; MpS[NW2 + 1] = 0; MgS[0] = 0; MgS[NW2 + 1] = 0; }

    // Stencil geometry: 8 bands x 8 rows. Waves 0-7 = rows 0-31 (A),
    // waves 8-15 = rows 32-63 (B).
    int qi = tid & 127, band = tid >> 7;
    int x4 = qi * 4;
    int ys = y0 + band * 8;
    float4 pm4 = make_float4(0, 0, 0, 0), pc4;
    if (ys > 0) pm4 = *(const float4*)(pimg + (size_t)(ys - 1) * W + x4);
    pc4 = *(const float4*)(pimg + (size_t)ys * W + x4);

    // pred edge colsums (cols 255,256), 64 center rows
    if (tid < 2 * TH2) {
        int c = tid >> 6, r = tid & (TH2 - 1);
        int y = y0 + r, col = 255 + c;
        float sum = (y > 0     ? pimg[(size_t)(y - 1) * W + col] : 0.f)
                  +              pimg[(size_t)y * W + col]
                  + (y < H - 1 ? pimg[(size_t)(y + 1) * W + col] : 0.f);
        EC[c][r] = sum;
    }
    __syncthreads();                      // barrier 1: masks ready

    // ---- Bit-sliced gt classification: 512 tasks (64 rows x 8 words) on
    // waves 0-7. Rows 0-31 -> waves 0-3 (A); rows 32-63 -> waves 4-7 (B).
    unsigned cge = 0, cgm = 0, cgj = 0;
    if (tid < 512) {
        int rr = tid >> 3, w = tid & 7;
        int oM = (HALO + rr) * 8 + w;
        bool wl = (w > 0), wr = (w < 7);
        uint64_t A  = Mg[oM - 8], Bm = Mg[oM], Cm = Mg[oM + 8];
        uint64_t AL = wl ? Mg[oM - 9] : 0ULL, AR = wr ? Mg[oM - 7] : 0ULL;
        uint64_t BL = wl ? Mg[oM - 1] : 0ULL, BR = wr ? Mg[oM + 1] : 0ULL;
        uint64_t CL = wl ? Mg[oM + 7] : 0ULL, CR = wr ? Mg[oM + 9] : 0ULL;
        uint64_t Aw = (A  << 1) | (AL >> 63), Ae = (A  >> 1) | (AR << 63);
        uint64_t Bw = (Bm << 1) | (BL >> 63), Be = (Bm >> 1) | (BR << 63);
        uint64_t Cw = (Cm << 1) | (CL >> 63), Ce = (Cm >> 1) | (CR << 63);
        uint64_t c1, c2, c3, c5, t;
        t = Aw ^ A;  uint64_t s1 = t ^ Ae;  c1 = (Aw & A)  | (Ae & t);
        t = Bw ^ Be; uint64_t s2 = t ^ Cw;  c2 = (Bw & Be) | (Cw & t);
        t = Cm ^ Ce; uint64_t s3 = t ^ s1;  c3 = (Cm & Ce) | (s1 & t);
        uint64_t b0 = s2 ^ s3, c4 = s2 & s3;
        t = c1 ^ c2; uint64_t s5 = t ^ c3;  c5 = (c1 & c2) | (c3 & t);
        uint64_t b1 = s5 ^ c4, c6 = s5 & c4;
        uint64_t b2 = c5 ^ c6, b3 = c5 & c6;
        uint64_t nz23 = ~(b2 | b3);
        uint64_t ge = Bm & b0 & ~b1 & nz23;
        uint64_t gm = Bm & b1 & ~b0 & nz23;
        uint64_t gj = Bm & (b2 | b3 | (b1 & b0));
        Ge[tid] = ge; Gm[tid] = gm; Gj[tid] = gj;
        cge = (unsigned)__popcll(ge);
        cgm = (unsigned)__popcll(gm);
        cgj = (unsigned)__popcll(gj);
    }

    // ---- Distance on ALL waves, u32 half-words (R9-proven cascade).
    // Waves 0-7: p2g; 8-15: g2p. Each thread: one A task + one B task.
    int dsA = 0, dcA = 0, dsB = 0, dcB = 0;
    {
        const uint32_t* Mp32 = (const uint32_t*)Mp;
        const uint32_t* Mg32 = (const uint32_t*)Mg;
        bool isP = tid < 512;
        int di = tid & 511;
        int h  = di & 15;
        bool wL = (h > 0), wR = (h < 15);
        const uint32_t* MT = isP ? Mp32 : Mg32;
        const uint32_t* MV = isP ? Mg32 : Mp32;
        int oA = (HALO + (di >> 4)) * 16 + h;

        #pragma unroll
        for (int half = 0; half < 2; ++half) {
            int o = oA + half * (32 * 16);     // B tasks are 32 rows below
            uint32_t T = MT[o];
            int dcnt = __popc(T);
            int dsum = dcnt;                   // a=0 baseline (dist >= 1)
            uint32_t VM = MV[o];
            uint32_t VL = wL ? MV[o - 1] : 0u;
            uint32_t VR = wR ? MV[o + 1] : 0u;
            uint32_t C = VM;
            #pragma unroll
            for (int a = 1; a <= 9; ++a) {
                int lo = o - 16 * a, hi = o + 16 * a;
                uint32_t NM = MV[lo] | MV[hi];
                uint32_t NL = wL ? (MV[lo - 1] | MV[hi - 1]) : 0u;
                uint32_t NR = wR ? (MV[lo + 1] | MV[hi + 1]) : 0u;
                uint32_t SL = NL, SM = NM, SR = NR;
                const int m = a - 1;
                if (m >= 1) {
                    SM |= (SM << 1) | (SM >> 1) | (SL >> 31) | (SR << 31);
                    SL |= SL << 1; SR |= SR >> 1;
                }
                if (m >= 2) {
                    const int s = (m == 2) ? 1 : 2;
                    SM |= (SM << s) | (SM >> s) | (SL >> (32 - s)) | (SR << (32 - s));
                    SL |= SL << s; SR |= SR >> s;
                }
                if (m >= 4) {
                    const int s = (m - 3 < 4) ? (m - 3) : 4;
                    SM |= (SM << s) | (SM >> s) | (SL >> (32 - s)) | (SR << (32 - s));
                    SL |= SL << s; SR |= SR >> s;
                }
                if (m >= 8) {
                    const int s = m - 7;
                    SM |= (SM << s) | (SM >> s) | (SL >> (32 - s)) | (SR << (32 - s));
                    SL |= SL << s; SR |= SR >> s;
                }
                C |= SM;
                VL |= NL; VM |= NM; VR |= NR;
                C |= (VM << a) | (VM >> a) | (VL >> (32 - a)) | (VR << (32 - a));
                uint32_t rem = T & ~C;
                dsum += __popc(rem);
                if (__all(rem == 0u)) break;   // bit-exact (C monotone)
            }
            if (half == 0) { dsA = dsum; dcA = dcnt; }
            else           { dsB = dsum; dcB = dcnt; }
        }
    }
    __syncthreads();                      // barrier 2: class masks ready

    // ---- Stencil: 8 rows per thread; pred rolling global float4, gt via
    // class-mask bit tests. Waves 0-7 accumulate A rows, 8-15 B rows.
    uint64_t cpack = 0ULL;                 // 6 fields, max 32 < 127
    {
        int wdx = qi >> 4;
        int ss = (qi & 15) * 4;
        for (int r = 0; r < 8; ++r) {
            int y = ys + r;
            float4 pp4 = (y < H - 1) ? *(const float4*)(pimg + (size_t)(y + 1) * W + x4)
                                     : make_float4(0, 0, 0, 0);
            int rr = band * 8 + r;
            uint64_t gew = Ge[rr * 8 + wdx];
            uint64_t gmw = Gm[rr * 8 + wdx];
            uint64_t gjw = Gj[rr * 8 + wdx];

            float ps[6];
            ps[1] = pm4.x + pc4.x + pp4.x; ps[2] = pm4.y + pc4.y + pp4.y;
            ps[3] = pm4.z + pc4.z + pp4.z; ps[4] = pm4.w + pc4.w + pp4.w;
            float psl = __shfl_up(ps[4], 1, 64);
            float psr = __shfl_down(ps[1], 1, 64);
            if (lane == 0)  psl = (qi == 0)   ? 0.f : EC[0][rr];
            if (lane == 63) psr = (qi == 127) ? 0.f : EC[1][rr];
            ps[0] = psl; ps[5] = psr;

            float pcv[4] = {pc4.x, pc4.y, pc4.z, pc4.w};
            #pragma unroll
            for (int j = 0; j < 4; ++j) {
                float np = ps[j] + ps[j + 1] + ps[j + 2] - pcv[j];
                bool pon = pcv[j] > 0.5f;
                bool pe  = pon && (np == 1.f);
                bool pmb = pon && (np == 2.f);
                bool pjb = pon && (np > 2.f);
                unsigned geb = (unsigned)(gew >> (ss + j)) & 1u;
                unsigned gmb = (unsigned)(gmw >> (ss + j)) & 1u;
                unsigned gjb = (unsigned)(gjw >> (ss + j)) & 1u;
                cpack += (uint64_t)pe
                       | ((uint64_t)pmb << 7)
                       | ((uint64_t)pjb << 14)
                       | ((uint64_t)(pe  && geb) << 21)
                       | ((uint64_t)(pmb && gmb) << 28)
                       | ((uint64_t)(pjb && gjb) << 35);
            }
            pm4 = pc4; pc4 = pp4;
        }
    }

    // ---- Packed reductions: 4 floats + 7 u32 (16-bit fields; bounds:
    // cpack fields <=64*32, class counts <=64*64, dsum <=64*320).
    unsigned c_pe = (unsigned)( cpack        & 0x7F);
    unsigned c_pm = (unsigned)((cpack >> 7 ) & 0x7F);
    unsigned c_pj = (unsigned)((cpack >> 14) & 0x7F);
    unsigned c_ie = (unsigned)((cpack >> 21) & 0x7F);
    unsigned c_im = (unsigned)((cpack >> 28) & 0x7F);
    unsigned c_ij = (unsigned)((cpack >> 35) & 0x7F);
    unsigned r0 = (unsigned)dsA | ((unsigned)dcA << 16);
    unsigned r1 = c_pe | (c_pm << 16);
    unsigned r2 = c_pj | (c_ie << 16);
    unsigned r3 = c_im | (c_ij << 16);
    unsigned r4 = cge | (cgm << 16);
    unsigned r5 = cgj;
    unsigned r6 = (unsigned)dsB | ((unsigned)dcB << 16);
    #pragma unroll
    for (int off = 32; off; off >>= 1) {
        v0A += __shfl_down(v0A, off, 64);
        v1A += __shfl_down(v1A, off, 64);
        v0B += __shfl_down(v0B, off, 64);
        v1B += __shfl_down(v1B, off, 64);
        r0 += __shfl_down(r0, off, 64);
        r1 += __shfl_down(r1, off, 64);
        r2 += __shfl_down(r2, off, 64);
        r3 += __shfl_down(r3, off, 64);
        r4 += __shfl_down(r4, off, 64);
        r5 += __shfl_down(r5, off, 64);
        r6 += __shfl_down(r6, off, 64);
    }
    if (lane == 0) {
        redfA[wid][0] = v0A; redfA[wid][1] = v1A;
        redfB[wid][0] = v0B; redfB[wid][1] = v1B;
        redu[wid][0] = r0; redu[wid][1] = r1; redu[wid][2] = r2;
        redu[wid][3] = r3; redu[wid][4] = r4; redu[wid][5] = r5;
        redu[wid][6] = r6;
    }
    __syncthreads();
    if (tid < 32) {
        int sub = tid >> 4, k = tid & 15;
        int fidT = (((t64 << 1) | sub) << 5) | b;    // tile32*32 + b
        float s = 0.f;
        if (k < 2) {
            const float (*rf)[2] = sub ? redfB : redfA;
            #pragma unroll
            for (int wv = 0; wv < NW; ++wv) s += rf[wv][k];
        } else {
            // per-(sub,k): wave base/count, redu reg, hi16
            static const uint8_t WB[2][16] = {
                {0,0, 8, 0,0,0, 0,0,0, 0,0,0, 0,0,8,8},
                {0,0, 8, 8,8,8, 4,4,4, 8,8,8, 0,0,8,8}};
            static const uint8_t WC[2][16] = {
                {0,0, 8, 8,8,8, 4,4,4, 8,8,8, 8,8,8,8},
                {0,0, 8, 8,8,8, 4,4,4, 8,8,8, 8,8,8,8}};
            static const uint8_t RG[2][16] = {
                {0,0, 0, 1,1,2, 4,4,5, 2,3,3, 0,0,0,0},
                {0,0, 6, 1,1,2, 4,4,5, 2,3,3, 6,6,6,6}};
            static const uint8_t HI[2][16] = {
                {0,0, 1, 0,1,0, 0,1,0, 1,0,1, 0,1,0,1},
                {0,0, 1, 0,1,0, 0,1,0, 1,0,1, 0,1,0,1}};
            unsigned u = 0;
            int wb = WB[sub][k], wc = WC[sub][k];
            int rg = RG[sub][k], hi = HI[sub][k];
            for (int wv = wb; wv < wb + wc; ++wv)
                u += (redu[wv][rg] >> (hi * 16)) & 0xFFFFu;
            s = (float)u;
        }
        part[fidT * NACC + k] = s;
    }
}

// ---------------------------------------------------------------------------
// Final: reduce 512x16 partials -> 32x16 -> scalar. Unchanged (bit-exact).
// ---------------------------------------------------------------------------
__global__ __launch_bounds__(512) void final_kernel(
    const float* __restrict__ part, float* __restrict__ out)
{
    __shared__ float sacc[BATCH][NACC];
    __shared__ float tri[BATCH][3];
    int t = threadIdx.x;
    {
        int b = t >> 4, k = t & 15;
        float s = 0.f;
        #pragma unroll 4
        for (int j = 0; j < NTILE; ++j)            // fid = j*32 + b
            s += part[((j << 5) + b) * NACC + k];
        sacc[b][k] = s;
    }
    __syncthreads();
    if (t < BATCH) {
        const float* a = sacc[t];
        float inter = a[0], psum = a[1], gsum = a[2];
        float dice = (2.f * inter + 1.f) / (psum + gsum + 1.f);

        float pe = a[3], pm = a[4], pj = a[5];
        float ge = a[6], gm = a[7], gj = a[8];
        float ie = a[9], im = a[10], ij = a[11];
        float e_iou = (ie + 1.f) / (pe + ge - ie + 1.f);
        float m_iou = (im + 1.f) / (pm + gm - im + 1.f);
        float j_iou = (ij + 1.f) / (pj + gj - ij + 1.f);
        float total = ge + gj + gm + 1.f;
        float sloss = 1.f - ((ge / total) * e_iou + (gj / total) * j_iou + (gm / total) * m_iou);

        float p2g = a[12] / (a[13] + 1.f);
        float g2p = a[14] / (a[15] + 1.f);
        float med = ((p2g + g2p) * 0.5f) / 10.f;
        tri[t][0] = dice; tri[t][1] = sloss; tri[t][2] = med;
    }
    __syncthreads();
    if (t == 0) {
        float dice = 0.f, sloss = 0.f, med = 0.f;
        for (int b = 0; b < BATCH; ++b) {
            dice += tri[b][0]; sloss += tri[b][1]; med += tri[b][2];
        }
        float dice_loss  = 1.f - dice / (float)BATCH;
        float structural = sloss / (float)BATCH;
        float medial     = med / (float)BATCH;
        float avg = (dice_loss + structural + medial) / 3.f;
        float r = dice_loss  / (dice_loss  + 1.f) * avg
                + structural / (structural + 1.f) * avg
                + medial     / (medial     + 1.f) * avg;
        out[0] = r;
    }
}

extern "C" void kernel_launch(void* const* d_in, const int* in_sizes, int n_in,
                              void* d_out, int out_size, void* d_ws, size_t ws_size,
                              hipStream_t stream)
{
    const float* pred = (const float*)d_in[0];
    const float* gt   = (const float*)d_in[1];
    float* part = (float*)d_ws;
    float* out  = (float*)d_out;

    fused_kernel<<<dim3(NBLK2), NT, 0, stream>>>(pred, gt, part);
    final_kernel<<<1, 512, 0, stream>>>(part, out);
}